// Round 3
// baseline (146.900 us; speedup 1.0000x reference)
//
#include <hip/hip_runtime.h>

#define N_    2
#define C_    128
#define H_    128
#define W_    128
#define COUT_ 128
#define K_    9
#define HO_   128
#define WO_   128
#define HW_   (H_*W_)

typedef __attribute__((ext_vector_type(8))) short short8v;   // 8 bf16 = 4 VGPR
typedef __attribute__((ext_vector_type(4))) float float4v;

__device__ __forceinline__ unsigned short f2bf(float f) {
    union { float f; unsigned int u; } v; v.f = f;
    return (unsigned short)((v.u + 0x7FFFu + ((v.u >> 16) & 1u)) >> 16);  // RNE
}

// ---- one-time weight pre-pack into MFMA A-fragment order -------------------
// wbuf[((kk*8 + mt)*4 + ks)*64 + lane] = 8 bf16: w[mt*16+(l&15)][ks*32+(l>>4)*8+j][kk]
__global__ __launch_bounds__(256)
void pack_w(const float* __restrict__ w, unsigned short* __restrict__ wb) {
    const int t = blockIdx.x * 256 + threadIdx.x;   // 0 .. 9*8*4*64-1
    if (t >= 9 * 8 * 4 * 64) return;
    const int l  = t & 63;
    const int ks = (t >> 6) & 3;
    const int mt = (t >> 8) & 7;
    const int kk = t >> 11;                          // 0..8
    const int row = mt * 16 + (l & 15);
    const int c0  = ks * 32 + (l >> 4) * 8;
    unsigned short pk[8];
    #pragma unroll
    for (int j = 0; j < 8; ++j)
        pk[j] = f2bf(w[row * (C_ * K_) + (c0 + j) * K_ + kk]);
    *((short8v*)wb + t) = *(short8v*)pk;
}

// ---- fused deformable-im2col + MFMA GEMM -----------------------------------
// 1024 blocks (n, ho, wo-quarter), XCD-swizzled; 4 blocks/CU, 16 waves/CU.
__global__ __launch_bounds__(256, 4)
void dcn_mfma(const float* __restrict__ x,
              const float* __restrict__ offset,
              const float* __restrict__ mask,
              const unsigned short* __restrict__ wbuf,
              const float* __restrict__ bias,
              float* __restrict__ out)
{
    __shared__ unsigned short colsT[32 * 128];       // 8 KB, XOR-swizzled [wo][c]

    const int tid = threadIdx.x;
    // XCD swizzle: 1024 blocks, 128 contiguous logical tiles per XCD ->
    // per-XCD x working set ~2.2 MB, fits the 4 MB private L2.
    const int lid = (blockIdx.x & 7) * 128 + (blockIdx.x >> 3);
    const int n   = lid >> 9;
    const int ho  = (lid >> 2) & 127;
    const int wo0 = (lid & 3) * 32;

    const int lane = tid & 63;
    const int wv   = tid >> 6;          // wave 0..3
    const int wol  = lane & 31;         // this lane's output column (0..31)
    const int cg   = lane >> 5;         // channel-half within the wave's 32-ch slice
    const int wo   = wo0 + wol;
    const int c0   = wv * 32 + cg * 16; // 16 channels gathered per lane per tap

    const float* xn = x + (size_t)n * C_ * HW_;
    const short8v* wb = (const short8v*)wbuf;

    const int mt0 = wv * 2;             // this wave's 2 cout-tiles of 16
    float4v acc[2][2] = {};             // 32 cout x 32 wo per wave

    for (int kk = 0; kk < K_; ++kk) {
        // ---- per-lane sampling metadata (registers, no LDS) ---------------
        const int iy = kk / 3, ix = kk % 3;
        const int ob = ((n * 2 * K_ + 2 * kk) * HO_ + ho) * WO_ + wo;
        const float offy = offset[ob];
        const float offx = offset[ob + HO_ * WO_];
        const float m    = mask[((n * K_ + kk) * HO_ + ho) * WO_ + wo];
        const float ys = (float)(ho - 1 + iy) + offy;
        const float xs = (float)(wo - 1 + ix) + offx;
        const float y0f = floorf(ys), x0f = floorf(xs);
        const float ly = ys - y0f, lx = xs - x0f;
        const int y0 = (int)y0f, x0 = (int)x0f;
        const int y1 = y0 + 1,  x1 = x0 + 1;
        const float vy0 = (y0 >= 0 && y0 < H_) ? 1.f : 0.f;
        const float vy1 = (y1 >= 0 && y1 < H_) ? 1.f : 0.f;
        const float vx0 = (x0 >= 0 && x0 < W_) ? 1.f : 0.f;
        const float vx1 = (x1 >= 0 && x1 < W_) ? 1.f : 0.f;
        const int y0c = min(max(y0, 0), H_-1), y1c = min(max(y1, 0), H_-1);
        const int x0c = min(max(x0, 0), W_-1), x1c = min(max(x1, 0), W_-1);
        const int a00 = y0c*W_ + x0c, a01 = y0c*W_ + x1c;
        const int a10 = y1c*W_ + x0c, a11 = y1c*W_ + x1c;
        const float w00 = (1.f-ly)*(1.f-lx)*m*vy0*vx0;
        const float w01 = (1.f-ly)*lx      *m*vy0*vx1;
        const float w10 = ly      *(1.f-lx)*m*vy1*vx0;
        const float w11 = ly      *lx      *m*vy1*vx1;

        // ---- gather 16 channels, batched loads for MLP --------------------
        unsigned short pk[16];
        #pragma unroll
        for (int half = 0; half < 2; ++half) {
            float v00[8], v01[8], v10[8], v11[8];
            #pragma unroll
            for (int cs = 0; cs < 8; ++cs) {
                const float* p = xn + (size_t)(c0 + half*8 + cs) * HW_;
                v00[cs] = p[a00]; v01[cs] = p[a01];
                v10[cs] = p[a10]; v11[cs] = p[a11];
            }
            #pragma unroll
            for (int cs = 0; cs < 8; ++cs)
                pk[half*8 + cs] = f2bf(w00*v00[cs] + w01*v01[cs]
                                     + w10*v10[cs] + w11*v11[cs]);
        }

        // ---- protect previous tap's MFMA reads, then publish --------------
        if (kk > 0) __syncthreads();
        {
            const int base = wol * 256 + c0 * 2;
            char* cb = (char*)colsT;
            *(short8v*)(cb + ((base     ) ^ ((wol & 7) << 4))) = *(short8v*)&pk[0];
            *(short8v*)(cb + ((base + 16) ^ ((wol & 7) << 4))) = *(short8v*)&pk[8];
        }
        __syncthreads();

        // ---- MFMA: 4 k-steps of 32 channels -------------------------------
        #pragma unroll
        for (int ks = 0; ks < 4; ++ks) {
            const short8v a0 = wb[((kk * 8 + mt0    ) * 4 + ks) * 64 + lane];
            const short8v a1 = wb[((kk * 8 + mt0 + 1) * 4 + ks) * 64 + lane];
            short8v b[2];
            #pragma unroll
            for (int nt = 0; nt < 2; ++nt) {
                const int row = nt * 16 + (lane & 15);
                const int byte = (row * 256 + ks * 64 + (lane >> 4) * 16)
                               ^ ((row & 7) << 4);
                b[nt] = *(const short8v*)((const char*)colsT + byte);
            }
            #pragma unroll
            for (int nt = 0; nt < 2; ++nt) {
                acc[0][nt] = __builtin_amdgcn_mfma_f32_16x16x32_bf16(a0, b[nt], acc[0][nt], 0, 0, 0);
                acc[1][nt] = __builtin_amdgcn_mfma_f32_16x16x32_bf16(a1, b[nt], acc[1][nt], 0, 0, 0);
            }
        }
    }

    // ---- epilogue: D layout col=lane&15 (wo), row=(lane>>4)*4+reg (cout) --
    const int colw  = lane & 15;
    const int rquad = (lane >> 4) * 4;
    #pragma unroll
    for (int mi = 0; mi < 2; ++mi) {
        #pragma unroll
        for (int nt = 0; nt < 2; ++nt) {
            const int woe = wo0 + nt * 16 + colw;
            #pragma unroll
            for (int r = 0; r < 4; ++r) {
                const int co = (mt0 + mi) * 16 + rquad + r;
                out[((size_t)(n * COUT_ + co) * HO_ + ho) * WO_ + woe] = acc[mi][nt][r] + bias[co];
            }
        }
    }
}

extern "C" void kernel_launch(void* const* d_in, const int* in_sizes, int n_in,
                              void* d_out, int out_size, void* d_ws, size_t ws_size,
                              hipStream_t stream) {
    const float* x      = (const float*)d_in[0];
    const float* offset = (const float*)d_in[1];
    const float* mask   = (const float*)d_in[2];
    const float* weight = (const float*)d_in[3];
    const float* bias   = (const float*)d_in[4];
    float* out = (float*)d_out;
    unsigned short* wbuf = (unsigned short*)d_ws;    // 294,912 B needed

    pack_w<<<72, 256, 0, stream>>>(weight, wbuf);
    dcn_mfma<<<N_ * HO_ * 4, 256, 0, stream>>>(x, offset, mask, wbuf, bias, out);
}

// Round 4
// 46.330 us; speedup vs baseline: 3.1707x; 3.1707x over previous
//
#include <hip/hip_runtime.h>

#define N_    2
#define C_    128
#define H_    128
#define W_    128
#define COUT_ 128
#define K_    9
#define HO_   128
#define WO_   128
#define HW_   (H_*W_)

typedef __attribute__((ext_vector_type(8))) short short8v;   // 8 bf16 = 4 VGPR
typedef __attribute__((ext_vector_type(4))) float float4v;

__device__ __forceinline__ unsigned short f2bf(float f) {
    union { float f; unsigned int u; } v; v.f = f;
    return (unsigned short)((v.u + 0x7FFFu + ((v.u >> 16) & 1u)) >> 16);  // RNE
}
__device__ __forceinline__ float bf2f(unsigned short u) {
    union { unsigned int u; float f; } v; v.u = ((unsigned int)u) << 16;
    return v.f;
}

// ---- one-time weight pre-pack into MFMA A-fragment order -------------------
__global__ __launch_bounds__(256)
void pack_w(const float* __restrict__ w, unsigned short* __restrict__ wb) {
    const int t = blockIdx.x * 256 + threadIdx.x;
    if (t >= 9 * 8 * 4 * 64) return;
    const int l  = t & 63;
    const int ks = (t >> 6) & 3;
    const int mt = (t >> 8) & 7;
    const int kk = t >> 11;
    const int row = mt * 16 + (l & 15);
    const int c0  = ks * 32 + (l >> 4) * 8;
    unsigned short pk[8];
    #pragma unroll
    for (int j = 0; j < 8; ++j)
        pk[j] = f2bf(w[row * (C_ * K_) + (c0 + j) * K_ + kk]);
    *((short8v*)wb + t) = *(short8v*)pk;
}

// ---- one-time CHW fp32 -> HWC bf16 transpose ------------------------------
// 256 blocks: each handles one n (bid>>7) and 128 pixels (p0 = (bid&127)*128).
__global__ __launch_bounds__(256)
void xpose(const float* __restrict__ x, unsigned short* __restrict__ xT) {
    __shared__ unsigned short tile[128][136];     // +8 pad: 2-way-free reads
    const int t  = threadIdx.x;
    const int n  = blockIdx.x >> 7;
    const int p0 = (blockIdx.x & 127) * 128;
    // read: coalesced along pixels, pack channel pairs into u32 LDS writes
    #pragma unroll 4
    for (int i = 0; i < 32; ++i) {
        const int q = i * 2 + (t >> 7);           // channel pair 0..63
        const int p = t & 127;
        const float v0 = x[((size_t)(n * C_ + 2 * q    )) * HW_ + p0 + p];
        const float v1 = x[((size_t)(n * C_ + 2 * q + 1)) * HW_ + p0 + p];
        const unsigned int u = (unsigned int)f2bf(v0) | ((unsigned int)f2bf(v1) << 16);
        *(unsigned int*)&tile[p][2 * q] = u;
    }
    __syncthreads();
    // write: each thread stores 128B contiguous of one pixel's channel row
    const int p    = t >> 1;
    const int half = t & 1;
    unsigned short* dst = xT + ((size_t)(n * HW_ + p0 + p) << 7) + half * 64;
    #pragma unroll
    for (int j = 0; j < 8; ++j)
        *(short8v*)(dst + j * 8) = *(short8v*)&tile[p][half * 64 + j * 8];
}

// ---- fused deformable-im2col + MFMA GEMM -----------------------------------
__global__ __launch_bounds__(256, 4)
void dcn_mfma(const unsigned short* __restrict__ xT,
              const float* __restrict__ offset,
              const float* __restrict__ mask,
              const unsigned short* __restrict__ wbuf,
              const float* __restrict__ bias,
              float* __restrict__ out)
{
    __shared__ unsigned short colsT[32 * 128];    // 8 KB, XOR-swizzled [wo][c]
    __shared__ int4   samp_a[K_ * 32];            // 4.6 KB pixel indices
    __shared__ float4 samp_w[K_ * 32];            // 4.6 KB premult bilinear wts

    const int tid = threadIdx.x;
    const int lid = (blockIdx.x & 7) * 128 + (blockIdx.x >> 3);  // XCD swizzle
    const int n   = lid >> 9;
    const int ho  = (lid >> 2) & 127;
    const int wo0 = (lid & 3) * 32;

    // ---- metadata for all 9 taps x 32 pixels (once) -----------------------
    for (int e = tid; e < K_ * 32; e += 256) {
        const int kk  = e >> 5;
        const int wol = e & 31;
        const int wo  = wo0 + wol;
        const int iy = kk / 3, ix = kk % 3;
        const int ob = ((n * 2 * K_ + 2 * kk) * HO_ + ho) * WO_ + wo;
        const float offy = offset[ob];
        const float offx = offset[ob + HO_ * WO_];
        const float m    = mask[((n * K_ + kk) * HO_ + ho) * WO_ + wo];
        const float ys = (float)(ho - 1 + iy) + offy;
        const float xs = (float)(wo - 1 + ix) + offx;
        const float y0f = floorf(ys), x0f = floorf(xs);
        const float ly = ys - y0f, lx = xs - x0f;
        const int y0 = (int)y0f, x0 = (int)x0f;
        const int y1 = y0 + 1,  x1 = x0 + 1;
        const float vy0 = (y0 >= 0 && y0 < H_) ? 1.f : 0.f;
        const float vy1 = (y1 >= 0 && y1 < H_) ? 1.f : 0.f;
        const float vx0 = (x0 >= 0 && x0 < W_) ? 1.f : 0.f;
        const float vx1 = (x1 >= 0 && x1 < W_) ? 1.f : 0.f;
        const int y0c = min(max(y0, 0), H_-1), y1c = min(max(y1, 0), H_-1);
        const int x0c = min(max(x0, 0), W_-1), x1c = min(max(x1, 0), W_-1);
        samp_a[e] = make_int4(y0c*W_+x0c, y0c*W_+x1c, y1c*W_+x0c, y1c*W_+x1c);
        samp_w[e] = make_float4((1.f-ly)*(1.f-lx)*m*vy0*vx0,
                                (1.f-ly)*lx      *m*vy0*vx1,
                                ly      *(1.f-lx)*m*vy1*vx0,
                                ly      *lx      *m*vy1*vx1);
    }
    __syncthreads();

    const int lane = tid & 63;
    const int wv   = tid >> 6;
    const int p    = tid >> 3;          // pixel 0..31
    const int s    = tid & 7;           // 16-channel chunk
    const int mt0  = wv * 2;
    float4v acc[2][2] = {};

    const char* xb = (const char*)xT + ((size_t)n * HW_) * 256;
    const short8v* wb = (const short8v*)wbuf;

    for (int kk = 0; kk < K_; ++kk) {
        // ---- dense NHWC gather: 8x 16B loads per thread -------------------
        const int4   av = samp_a[kk * 32 + p];
        const float4 w4 = samp_w[kk * 32 + p];
        const int so = s * 32;
        const short8v g00a = *(const short8v*)(xb + (size_t)av.x * 256 + so);
        const short8v g00b = *(const short8v*)(xb + (size_t)av.x * 256 + so + 16);
        const short8v g01a = *(const short8v*)(xb + (size_t)av.y * 256 + so);
        const short8v g01b = *(const short8v*)(xb + (size_t)av.y * 256 + so + 16);
        const short8v g10a = *(const short8v*)(xb + (size_t)av.z * 256 + so);
        const short8v g10b = *(const short8v*)(xb + (size_t)av.z * 256 + so + 16);
        const short8v g11a = *(const short8v*)(xb + (size_t)av.w * 256 + so);
        const short8v g11b = *(const short8v*)(xb + (size_t)av.w * 256 + so + 16);

        unsigned short pk[16];
        #pragma unroll
        for (int j = 0; j < 8; ++j) {
            const float va = w4.x * bf2f((unsigned short)g00a[j])
                           + w4.y * bf2f((unsigned short)g01a[j])
                           + w4.z * bf2f((unsigned short)g10a[j])
                           + w4.w * bf2f((unsigned short)g11a[j]);
            const float vb = w4.x * bf2f((unsigned short)g00b[j])
                           + w4.y * bf2f((unsigned short)g01b[j])
                           + w4.z * bf2f((unsigned short)g10b[j])
                           + w4.w * bf2f((unsigned short)g11b[j]);
            pk[j]     = f2bf(va);
            pk[8 + j] = f2bf(vb);
        }

        if (kk > 0) __syncthreads();    // protect previous tap's B-reads
        {
            char* cb = (char*)colsT;
            const int base = p * 256 + so;
            const int swz  = (p & 7) << 4;
            *(short8v*)(cb + ((base     ) ^ swz)) = *(short8v*)&pk[0];
            *(short8v*)(cb + ((base + 16) ^ swz)) = *(short8v*)&pk[8];
        }
        __syncthreads();

        // ---- MFMA: 4 k-steps of 32 channels -------------------------------
        #pragma unroll
        for (int ks = 0; ks < 4; ++ks) {
            const short8v a0 = wb[((kk * 8 + mt0    ) * 4 + ks) * 64 + lane];
            const short8v a1 = wb[((kk * 8 + mt0 + 1) * 4 + ks) * 64 + lane];
            short8v b[2];
            #pragma unroll
            for (int nt = 0; nt < 2; ++nt) {
                const int row = nt * 16 + (lane & 15);
                const int byte = (row * 256 + ks * 64 + (lane >> 4) * 16)
                               ^ ((row & 7) << 4);
                b[nt] = *(const short8v*)((const char*)colsT + byte);
            }
            #pragma unroll
            for (int nt = 0; nt < 2; ++nt) {
                acc[0][nt] = __builtin_amdgcn_mfma_f32_16x16x32_bf16(a0, b[nt], acc[0][nt], 0, 0, 0);
                acc[1][nt] = __builtin_amdgcn_mfma_f32_16x16x32_bf16(a1, b[nt], acc[1][nt], 0, 0, 0);
            }
        }
    }

    // ---- epilogue: D layout col=lane&15 (wo), row=(lane>>4)*4+reg (cout) --
    const int colw  = lane & 15;
    const int rquad = (lane >> 4) * 4;
    #pragma unroll
    for (int mi = 0; mi < 2; ++mi) {
        #pragma unroll
        for (int nt = 0; nt < 2; ++nt) {
            const int woe = wo0 + nt * 16 + colw;
            #pragma unroll
            for (int r = 0; r < 4; ++r) {
                const int co = (mt0 + mi) * 16 + rquad + r;
                out[((size_t)(n * COUT_ + co) * HO_ + ho) * WO_ + woe] = acc[mi][nt][r] + bias[co];
            }
        }
    }
}

extern "C" void kernel_launch(void* const* d_in, const int* in_sizes, int n_in,
                              void* d_out, int out_size, void* d_ws, size_t ws_size,
                              hipStream_t stream) {
    const float* x      = (const float*)d_in[0];
    const float* offset = (const float*)d_in[1];
    const float* mask   = (const float*)d_in[2];
    const float* weight = (const float*)d_in[3];
    const float* bias   = (const float*)d_in[4];
    float* out = (float*)d_out;

    unsigned short* xT   = (unsigned short*)d_ws;                 // 8,388,608 B
    unsigned short* wbuf = (unsigned short*)((char*)d_ws + 8388608); // +294,912 B

    pack_w<<<72, 256, 0, stream>>>(weight, wbuf);
    xpose <<<256, 256, 0, stream>>>(x, xT);
    dcn_mfma<<<N_ * HO_ * 4, 256, 0, stream>>>(xT, offset, mask, wbuf, bias, out);
}

// Round 5
// 42.643 us; speedup vs baseline: 3.4449x; 1.0865x over previous
//
#include <hip/hip_runtime.h>

#define N_    2
#define C_    128
#define H_    128
#define W_    128
#define COUT_ 128
#define K_    9
#define HO_   128
#define WO_   128
#define HW_   (H_*W_)

typedef __attribute__((ext_vector_type(8))) short  short8v;
typedef __attribute__((ext_vector_type(4))) float  float4v;
typedef __attribute__((ext_vector_type(2))) float  float2v;
typedef __attribute__((ext_vector_type(4))) unsigned int uint4v;

__device__ __forceinline__ unsigned short f2bf(float f) {
    union { float f; unsigned int u; } v; v.f = f;
    return (unsigned short)((v.u + 0x7FFFu + ((v.u >> 16) & 1u)) >> 16);  // RNE
}
__device__ __forceinline__ float bflo(unsigned int u) {
    union { unsigned int u; float f; } v; v.u = u << 16; return v.f;
}
__device__ __forceinline__ float bfhi(unsigned int u) {
    union { unsigned int u; float f; } v; v.u = u & 0xFFFF0000u; return v.f;
}

// ---- one-time prep: weight pack (A-fragment order) + CHW->HWC bf16 --------
__global__ __launch_bounds__(256)
void prep(const float* __restrict__ x, const float* __restrict__ w,
          unsigned short* __restrict__ xT, unsigned short* __restrict__ wb) {
    if (blockIdx.x >= 256) {                       // ---- pack_w part
        const int t = (blockIdx.x - 256) * 256 + threadIdx.x;
        if (t >= 9 * 8 * 4 * 64) return;
        const int l  = t & 63;
        const int ks = (t >> 6) & 3;
        const int mt = (t >> 8) & 7;
        const int kk = t >> 11;
        const int row = mt * 16 + (l & 15);
        const int c0  = ks * 32 + (l >> 4) * 8;
        unsigned short pk[8];
        #pragma unroll
        for (int j = 0; j < 8; ++j)
            pk[j] = f2bf(w[row * (C_ * K_) + (c0 + j) * K_ + kk]);
        *((short8v*)wb + t) = *(short8v*)pk;
        return;
    }
    // ---- xpose part: one n (bid>>7), 128 pixels
    __shared__ unsigned short tile[128][136];
    const int t  = threadIdx.x;
    const int n  = blockIdx.x >> 7;
    const int p0 = (blockIdx.x & 127) * 128;
    #pragma unroll 4
    for (int i = 0; i < 32; ++i) {
        const int q = i * 2 + (t >> 7);
        const int p = t & 127;
        const float v0 = x[((size_t)(n * C_ + 2 * q    )) * HW_ + p0 + p];
        const float v1 = x[((size_t)(n * C_ + 2 * q + 1)) * HW_ + p0 + p];
        const unsigned int u = (unsigned int)f2bf(v0) | ((unsigned int)f2bf(v1) << 16);
        *(unsigned int*)&tile[p][2 * q] = u;
    }
    __syncthreads();
    const int p    = t >> 1;
    const int half = t & 1;
    unsigned short* dst = xT + ((size_t)(n * HW_ + p0 + p) << 7) + half * 64;
    #pragma unroll
    for (int j = 0; j < 8; ++j)
        *(short8v*)(dst + j * 8) = *(short8v*)&tile[p][half * 64 + j * 8];
}

// ---- fused deformable-im2col + MFMA GEMM, cross-tap pipelined -------------
__global__ __launch_bounds__(256, 4)
void dcn_mfma(const unsigned short* __restrict__ xT,
              const float* __restrict__ offset,
              const float* __restrict__ mask,
              const unsigned short* __restrict__ wbuf,
              const float* __restrict__ bias,
              float* __restrict__ out)
{
    __shared__ unsigned short colsT[2][32 * 128]; // 16 KB double-buffered
    __shared__ int4   samp_a[K_ * 32];            // 4.6 KB
    __shared__ float4 samp_w[K_ * 32];            // 4.6 KB

    const int tid = threadIdx.x;
    const int lid = (blockIdx.x & 7) * 128 + (blockIdx.x >> 3);  // XCD swizzle
    const int n   = lid >> 9;
    const int ho  = (lid >> 2) & 127;
    const int wo0 = (lid & 3) * 32;

    // ---- metadata for all 9 taps x 32 pixels ------------------------------
    for (int e = tid; e < K_ * 32; e += 256) {
        const int kk  = e >> 5;
        const int wol = e & 31;
        const int wo  = wo0 + wol;
        const int iy = kk / 3, ix = kk % 3;
        const int ob = ((n * 2 * K_ + 2 * kk) * HO_ + ho) * WO_ + wo;
        const float offy = offset[ob];
        const float offx = offset[ob + HO_ * WO_];
        const float m    = mask[((n * K_ + kk) * HO_ + ho) * WO_ + wo];
        const float ys = (float)(ho - 1 + iy) + offy;
        const float xs = (float)(wo - 1 + ix) + offx;
        const float y0f = floorf(ys), x0f = floorf(xs);
        const float ly = ys - y0f, lx = xs - x0f;
        const int y0 = (int)y0f, x0 = (int)x0f;
        const int y1 = y0 + 1,  x1 = x0 + 1;
        const float vy0 = (y0 >= 0 && y0 < H_) ? 1.f : 0.f;
        const float vy1 = (y1 >= 0 && y1 < H_) ? 1.f : 0.f;
        const float vx0 = (x0 >= 0 && x0 < W_) ? 1.f : 0.f;
        const float vx1 = (x1 >= 0 && x1 < W_) ? 1.f : 0.f;
        const int y0c = min(max(y0, 0), H_-1), y1c = min(max(y1, 0), H_-1);
        const int x0c = min(max(x0, 0), W_-1), x1c = min(max(x1, 0), W_-1);
        samp_a[e] = make_int4(y0c*W_+x0c, y0c*W_+x1c, y1c*W_+x0c, y1c*W_+x1c);
        samp_w[e] = make_float4((1.f-ly)*(1.f-lx)*m*vy0*vx0,
                                (1.f-ly)*lx      *m*vy0*vx1,
                                ly      *(1.f-lx)*m*vy1*vx0,
                                ly      *lx      *m*vy1*vx1);
    }
    __syncthreads();

    const int lane = tid & 63;
    const int wv   = tid >> 6;
    const int p    = tid >> 3;          // pixel 0..31
    const int s    = tid & 7;           // 16-channel chunk
    const int so   = s * 32;            // byte offset within a pixel's 256B row
    const int mt0  = wv * 2;
    float4v acc[2][2] = {};

    const char* xb = (const char*)xT + ((size_t)n * HW_) * 256;
    const short8v* wb = (const short8v*)wbuf;

    // double-buffered prefetch registers (static-indexed after full unroll)
    uint4v ga[2][4][2];                 // [parity][corner][half16B]
    float4 w4v[2];

    // ---- prologue: issue tap-0 gathers ------------------------------------
    {
        const int4 a0 = samp_a[p];
        w4v[0] = samp_w[p];
        const char* b0 = xb + (size_t)a0.x * 256 + so;
        const char* b1 = xb + (size_t)a0.y * 256 + so;
        const char* b2 = xb + (size_t)a0.z * 256 + so;
        const char* b3 = xb + (size_t)a0.w * 256 + so;
        ga[0][0][0] = *(const uint4v*)b0;  ga[0][0][1] = *(const uint4v*)(b0 + 16);
        ga[0][1][0] = *(const uint4v*)b1;  ga[0][1][1] = *(const uint4v*)(b1 + 16);
        ga[0][2][0] = *(const uint4v*)b2;  ga[0][2][1] = *(const uint4v*)(b2 + 16);
        ga[0][3][0] = *(const uint4v*)b3;  ga[0][3][1] = *(const uint4v*)(b3 + 16);
    }

    #pragma unroll
    for (int kk = 0; kk < K_; ++kk) {
        const int cur = kk & 1, nxt = cur ^ 1;

        // ---- packed bilinear combine (v_pk_fma_f32) -----------------------
        const float2v wx = {w4v[cur].x, w4v[cur].x};
        const float2v wy = {w4v[cur].y, w4v[cur].y};
        const float2v wz = {w4v[cur].z, w4v[cur].z};
        const float2v ww = {w4v[cur].w, w4v[cur].w};
        uint4v res[2];
        #pragma unroll
        for (int h = 0; h < 2; ++h)
            #pragma unroll
            for (int j = 0; j < 4; ++j) {
                const unsigned int u00 = ga[cur][0][h][j], u01 = ga[cur][1][h][j];
                const unsigned int u10 = ga[cur][2][h][j], u11 = ga[cur][3][h][j];
                const float2v f00 = {bflo(u00), bfhi(u00)};
                const float2v f01 = {bflo(u01), bfhi(u01)};
                const float2v f10 = {bflo(u10), bfhi(u10)};
                const float2v f11 = {bflo(u11), bfhi(u11)};
                const float2v v = wx*f00 + wy*f01 + wz*f10 + ww*f11;
                res[h][j] = (unsigned int)f2bf(v[0]) | ((unsigned int)f2bf(v[1]) << 16);
            }

        // ---- publish into LDS buffer `cur` --------------------------------
        {
            char* cb = (char*)colsT[cur];
            const int base = p * 256 + so;
            const int swz  = (p & 7) << 4;
            *(uint4v*)(cb + ((base     ) ^ swz)) = res[0];
            *(uint4v*)(cb + ((base + 16) ^ swz)) = res[1];
        }

        // ---- prefetch tap kk+1 (issue before barrier & MFMA) --------------
        if (kk < K_ - 1) {
            const int4 a1 = samp_a[(kk + 1) * 32 + p];
            w4v[nxt] = samp_w[(kk + 1) * 32 + p];
            const char* b0 = xb + (size_t)a1.x * 256 + so;
            const char* b1 = xb + (size_t)a1.y * 256 + so;
            const char* b2 = xb + (size_t)a1.z * 256 + so;
            const char* b3 = xb + (size_t)a1.w * 256 + so;
            ga[nxt][0][0] = *(const uint4v*)b0;  ga[nxt][0][1] = *(const uint4v*)(b0 + 16);
            ga[nxt][1][0] = *(const uint4v*)b1;  ga[nxt][1][1] = *(const uint4v*)(b1 + 16);
            ga[nxt][2][0] = *(const uint4v*)b2;  ga[nxt][2][1] = *(const uint4v*)(b2 + 16);
            ga[nxt][3][0] = *(const uint4v*)b3;  ga[nxt][3][1] = *(const uint4v*)(b3 + 16);
        }

        __syncthreads();   // single barrier per tap (dbuf makes WAR safe)

        // ---- MFMA: 4 k-steps of 32 channels from buffer `cur` -------------
        #pragma unroll
        for (int ks = 0; ks < 4; ++ks) {
            const short8v a0 = wb[((kk * 8 + mt0    ) * 4 + ks) * 64 + lane];
            const short8v a1 = wb[((kk * 8 + mt0 + 1) * 4 + ks) * 64 + lane];
            short8v b[2];
            #pragma unroll
            for (int nt = 0; nt < 2; ++nt) {
                const int row = nt * 16 + (lane & 15);
                const int byte = (row * 256 + ks * 64 + (lane >> 4) * 16)
                               ^ ((row & 7) << 4);
                b[nt] = *(const short8v*)((const char*)colsT[cur] + byte);
            }
            #pragma unroll
            for (int nt = 0; nt < 2; ++nt) {
                acc[0][nt] = __builtin_amdgcn_mfma_f32_16x16x32_bf16(a0, b[nt], acc[0][nt], 0, 0, 0);
                acc[1][nt] = __builtin_amdgcn_mfma_f32_16x16x32_bf16(a1, b[nt], acc[1][nt], 0, 0, 0);
            }
        }
    }

    // ---- epilogue: D layout col=lane&15 (wo), row=(lane>>4)*4+reg (cout) --
    const int colw  = lane & 15;
    const int rquad = (lane >> 4) * 4;
    #pragma unroll
    for (int mi = 0; mi < 2; ++mi) {
        #pragma unroll
        for (int nt = 0; nt < 2; ++nt) {
            const int woe = wo0 + nt * 16 + colw;
            #pragma unroll
            for (int r = 0; r < 4; ++r) {
                const int co = (mt0 + mi) * 16 + rquad + r;
                out[((size_t)(n * COUT_ + co) * HO_ + ho) * WO_ + woe] = acc[mi][nt][r] + bias[co];
            }
        }
    }
}

extern "C" void kernel_launch(void* const* d_in, const int* in_sizes, int n_in,
                              void* d_out, int out_size, void* d_ws, size_t ws_size,
                              hipStream_t stream) {
    const float* x      = (const float*)d_in[0];
    const float* offset = (const float*)d_in[1];
    const float* mask   = (const float*)d_in[2];
    const float* weight = (const float*)d_in[3];
    const float* bias   = (const float*)d_in[4];
    float* out = (float*)d_out;

    unsigned short* xT   = (unsigned short*)d_ws;                    // 8,388,608 B
    unsigned short* wbuf = (unsigned short*)((char*)d_ws + 8388608); // +294,912 B

    prep<<<328, 256, 0, stream>>>(x, weight, xT, wbuf);
    dcn_mfma<<<N_ * HO_ * 4, 256, 0, stream>>>(xT, offset, mask, wbuf, bias, out);
}

// Round 6
// 40.423 us; speedup vs baseline: 3.6340x; 1.0549x over previous
//
#include <hip/hip_runtime.h>

#define N_    2
#define C_    128
#define H_    128
#define W_    128
#define COUT_ 128
#define K_    9
#define HO_   128
#define WO_   128
#define HW_   (H_*W_)

typedef __attribute__((ext_vector_type(8))) short  short8v;
typedef __attribute__((ext_vector_type(4))) float  float4v;
typedef __attribute__((ext_vector_type(2))) float  float2v;
typedef __attribute__((ext_vector_type(4))) unsigned int uint4v;

__device__ __forceinline__ unsigned short f2bf(float f) {
    union { float f; unsigned int u; } v; v.f = f;
    return (unsigned short)((v.u + 0x7FFFu + ((v.u >> 16) & 1u)) >> 16);  // RNE
}
__device__ __forceinline__ float bflo(unsigned int u) {
    union { unsigned int u; float f; } v; v.u = u << 16; return v.f;
}
__device__ __forceinline__ float bfhi(unsigned int u) {
    union { unsigned int u; float f; } v; v.u = u & 0xFFFF0000u; return v.f;
}

// ---- one-time prep: weight pack (A-fragment order) + CHW->HWC bf16 --------
__global__ __launch_bounds__(256)
void prep(const float* __restrict__ x, const float* __restrict__ w,
          unsigned short* __restrict__ xT, unsigned short* __restrict__ wb) {
    if (blockIdx.x >= 256) {                       // ---- pack_w part
        const int t = (blockIdx.x - 256) * 256 + threadIdx.x;
        if (t >= 9 * 8 * 4 * 64) return;
        const int l  = t & 63;
        const int ks = (t >> 6) & 3;
        const int mt = (t >> 8) & 7;
        const int kk = t >> 11;
        const int row = mt * 16 + (l & 15);
        const int c0  = ks * 32 + (l >> 4) * 8;
        unsigned short pk[8];
        #pragma unroll
        for (int j = 0; j < 8; ++j)
            pk[j] = f2bf(w[row * (C_ * K_) + (c0 + j) * K_ + kk]);
        *((short8v*)wb + t) = *(short8v*)pk;
        return;
    }
    // ---- xpose part: one n (bid>>7), 128 pixels
    __shared__ unsigned short tile[128][136];
    const int t  = threadIdx.x;
    const int n  = blockIdx.x >> 7;
    const int p0 = (blockIdx.x & 127) * 128;
    #pragma unroll 4
    for (int i = 0; i < 32; ++i) {
        const int q = i * 2 + (t >> 7);
        const int p = t & 127;
        const float v0 = x[((size_t)(n * C_ + 2 * q    )) * HW_ + p0 + p];
        const float v1 = x[((size_t)(n * C_ + 2 * q + 1)) * HW_ + p0 + p];
        const unsigned int u = (unsigned int)f2bf(v0) | ((unsigned int)f2bf(v1) << 16);
        *(unsigned int*)&tile[p][2 * q] = u;
    }
    __syncthreads();
    const int p    = t >> 1;
    const int half = t & 1;
    unsigned short* dst = xT + ((size_t)(n * HW_ + p0 + p) << 7) + half * 64;
    #pragma unroll
    for (int j = 0; j < 8; ++j)
        *(short8v*)(dst + j * 8) = *(short8v*)&tile[p][half * 64 + j * 8];
}

// ---- fused deformable-im2col + MFMA GEMM -----------------------------------
// 512 blocks x 512 threads. Block = 64 px row-segment; wave = 16 cout x 64 px.
// Single NON-draining barrier per tap: gather/A prefetch survive across it.
__global__ __launch_bounds__(512, 4)
void dcn_mfma(const unsigned short* __restrict__ xT,
              const float* __restrict__ offset,
              const float* __restrict__ mask,
              const unsigned short* __restrict__ wbuf,
              const float* __restrict__ bias,
              float* __restrict__ out)
{
    __shared__ unsigned short colsT[2][64 * 128]; // 32 KB double-buffered
    __shared__ int4   samp_a[K_ * 64];            // 9.2 KB
    __shared__ float4 samp_w[K_ * 64];            // 9.2 KB

    const int tid = threadIdx.x;
    const int lid = (blockIdx.x & 7) * 64 + (blockIdx.x >> 3);  // XCD swizzle
    const int n   = lid >> 8;
    const int ho  = (lid >> 1) & 127;
    const int wo0 = (lid & 1) * 64;

    // ---- metadata for all 9 taps x 64 pixels ------------------------------
    for (int e = tid; e < K_ * 64; e += 512) {
        const int kk  = e >> 6;
        const int wol = e & 63;
        const int wo  = wo0 + wol;
        const int iy = kk / 3, ix = kk % 3;
        const int ob = ((n * 2 * K_ + 2 * kk) * HO_ + ho) * WO_ + wo;
        const float offy = offset[ob];
        const float offx = offset[ob + HO_ * WO_];
        const float m    = mask[((n * K_ + kk) * HO_ + ho) * WO_ + wo];
        const float ys = (float)(ho - 1 + iy) + offy;
        const float xs = (float)(wo - 1 + ix) + offx;
        const float y0f = floorf(ys), x0f = floorf(xs);
        const float ly = ys - y0f, lx = xs - x0f;
        const int y0 = (int)y0f, x0 = (int)x0f;
        const int y1 = y0 + 1,  x1 = x0 + 1;
        const float vy0 = (y0 >= 0 && y0 < H_) ? 1.f : 0.f;
        const float vy1 = (y1 >= 0 && y1 < H_) ? 1.f : 0.f;
        const float vx0 = (x0 >= 0 && x0 < W_) ? 1.f : 0.f;
        const float vx1 = (x1 >= 0 && x1 < W_) ? 1.f : 0.f;
        const int y0c = min(max(y0, 0), H_-1), y1c = min(max(y1, 0), H_-1);
        const int x0c = min(max(x0, 0), W_-1), x1c = min(max(x1, 0), W_-1);
        samp_a[e] = make_int4(y0c*W_+x0c, y0c*W_+x1c, y1c*W_+x0c, y1c*W_+x1c);
        samp_w[e] = make_float4((1.f-ly)*(1.f-lx)*m*vy0*vx0,
                                (1.f-ly)*lx      *m*vy0*vx1,
                                ly      *(1.f-lx)*m*vy1*vx0,
                                ly      *lx      *m*vy1*vx1);
    }
    __syncthreads();

    const int lane = tid & 63;
    const int wv   = tid >> 6;          // wave 0..7 = cout tile
    const int p    = tid >> 3;          // pixel 0..63
    const int s    = tid & 7;           // 16-channel chunk
    const int so   = s * 32;
    float4v acc[4] = {};                // 16 cout x 64 wo per wave

    const char* xb = (const char*)xT + ((size_t)n * HW_) * 256;
    const short8v* wb = (const short8v*)wbuf;

    // ---- prologue: issue tap-0 gathers ------------------------------------
    uint4v ga[4][2];
    float4 w4;
    {
        const int4 a0 = samp_a[p];
        w4 = samp_w[p];
        const char* b0 = xb + (size_t)a0.x * 256 + so;
        const char* b1 = xb + (size_t)a0.y * 256 + so;
        const char* b2 = xb + (size_t)a0.z * 256 + so;
        const char* b3 = xb + (size_t)a0.w * 256 + so;
        ga[0][0] = *(const uint4v*)b0;  ga[0][1] = *(const uint4v*)(b0 + 16);
        ga[1][0] = *(const uint4v*)b1;  ga[1][1] = *(const uint4v*)(b1 + 16);
        ga[2][0] = *(const uint4v*)b2;  ga[2][1] = *(const uint4v*)(b2 + 16);
        ga[3][0] = *(const uint4v*)b3;  ga[3][1] = *(const uint4v*)(b3 + 16);
    }

    #pragma unroll
    for (int kk = 0; kk < K_; ++kk) {
        const int cur = kk & 1;

        // ---- issue this tap's A-fragments (land during combine) -----------
        short8v af[4];
        #pragma unroll
        for (int ks = 0; ks < 4; ++ks)
            af[ks] = wb[((kk * 8 + wv) * 4 + ks) * 64 + lane];

        // ---- packed bilinear combine --------------------------------------
        const float2v wx = {w4.x, w4.x};
        const float2v wy = {w4.y, w4.y};
        const float2v wz = {w4.z, w4.z};
        const float2v ww = {w4.w, w4.w};
        uint4v res[2];
        #pragma unroll
        for (int h = 0; h < 2; ++h)
            #pragma unroll
            for (int j = 0; j < 4; ++j) {
                const unsigned int u00 = ga[0][h][j], u01 = ga[1][h][j];
                const unsigned int u10 = ga[2][h][j], u11 = ga[3][h][j];
                const float2v f00 = {bflo(u00), bfhi(u00)};
                const float2v f01 = {bflo(u01), bfhi(u01)};
                const float2v f10 = {bflo(u10), bfhi(u10)};
                const float2v f11 = {bflo(u11), bfhi(u11)};
                const float2v v = wx*f00 + wy*f01 + wz*f10 + ww*f11;
                res[h][j] = (unsigned int)f2bf(v[0]) | ((unsigned int)f2bf(v[1]) << 16);
            }

        // ---- prefetch tap kk+1 gathers (land during barrier+MFMA) ---------
        if (kk < K_ - 1) {
            const int4 a1 = samp_a[(kk + 1) * 64 + p];
            w4 = samp_w[(kk + 1) * 64 + p];
            const char* b0 = xb + (size_t)a1.x * 256 + so;
            const char* b1 = xb + (size_t)a1.y * 256 + so;
            const char* b2 = xb + (size_t)a1.z * 256 + so;
            const char* b3 = xb + (size_t)a1.w * 256 + so;
            ga[0][0] = *(const uint4v*)b0;  ga[0][1] = *(const uint4v*)(b0 + 16);
            ga[1][0] = *(const uint4v*)b1;  ga[1][1] = *(const uint4v*)(b1 + 16);
            ga[2][0] = *(const uint4v*)b2;  ga[2][1] = *(const uint4v*)(b2 + 16);
            ga[3][0] = *(const uint4v*)b3;  ga[3][1] = *(const uint4v*)(b3 + 16);
        }

        // ---- publish into LDS buffer `cur` --------------------------------
        {
            char* cb = (char*)colsT[cur];
            const int base = p * 256 + so;
            const int swz  = (p & 7) << 4;
            *(uint4v*)(cb + ((base     ) ^ swz)) = res[0];
            *(uint4v*)(cb + ((base + 16) ^ swz)) = res[1];
        }

        // ---- non-draining barrier: only LDS writes drained; VMEM in flight
        asm volatile("s_waitcnt lgkmcnt(0)" ::: "memory");
        __builtin_amdgcn_s_barrier();

        // ---- MFMA: 4 k-steps x 4 n-tiles from buffer `cur` ----------------
        #pragma unroll
        for (int ks = 0; ks < 4; ++ks) {
            short8v b[4];
            #pragma unroll
            for (int nt = 0; nt < 4; ++nt) {
                const int row = nt * 16 + (lane & 15);
                const int byte = (row * 256 + ks * 64 + (lane >> 4) * 16)
                               ^ ((row & 7) << 4);
                b[nt] = *(const short8v*)((const char*)colsT[cur] + byte);
            }
            #pragma unroll
            for (int nt = 0; nt < 4; ++nt)
                acc[nt] = __builtin_amdgcn_mfma_f32_16x16x32_bf16(af[ks], b[nt], acc[nt], 0, 0, 0);
        }
    }

    // ---- epilogue: D layout col=lane&15 (wo), row=(lane>>4)*4+reg (cout) --
    const int colw  = lane & 15;
    const int rquad = (lane >> 4) * 4;
    #pragma unroll
    for (int nt = 0; nt < 4; ++nt) {
        const int woe = wo0 + nt * 16 + colw;
        #pragma unroll
        for (int r = 0; r < 4; ++r) {
            const int co = wv * 16 + rquad + r;
            out[((size_t)(n * COUT_ + co) * HO_ + ho) * WO_ + woe] = acc[nt][r] + bias[co];
        }
    }
}

extern "C" void kernel_launch(void* const* d_in, const int* in_sizes, int n_in,
                              void* d_out, int out_size, void* d_ws, size_t ws_size,
                              hipStream_t stream) {
    const float* x      = (const float*)d_in[0];
    const float* offset = (const float*)d_in[1];
    const float* mask   = (const float*)d_in[2];
    const float* weight = (const float*)d_in[3];
    const float* bias   = (const float*)d_in[4];
    float* out = (float*)d_out;

    unsigned short* xT   = (unsigned short*)d_ws;                    // 8,388,608 B
    unsigned short* wbuf = (unsigned short*)((char*)d_ws + 8388608); // +294,912 B

    prep<<<328, 256, 0, stream>>>(x, weight, xT, wbuf);
    dcn_mfma<<<N_ * HO_ * 2, 512, 0, stream>>>(xT, offset, mask, wbuf, bias, out);
}